// Round 8
// baseline (117.211 us; speedup 1.0000x reference)
//
#include <hip/hip_runtime.h>
#include <hip/hip_bf16.h>

typedef __attribute__((ext_vector_type(8))) short bf16x8;
typedef __attribute__((ext_vector_type(4))) short s16x4;
typedef __attribute__((ext_vector_type(4))) float f32x4;
typedef __attribute__((ext_vector_type(4))) int   i32x4;

#define N_IN  128
#define N_HID 64
#define LDS_PAD 8      // bf16 elements of pad per row
#define TPB 256
#define WAVES_PER_BLOCK 4

// scalar RNE f32->bf16 (one-time W1 staging only)
static __device__ inline short f2bf(float f) {
    unsigned u = __float_as_uint(f);
    u += 0x7fffu + ((u >> 16) & 1u);
    return (short)(u >> 16);
}

// HW packed convert: 8 f32 -> 8 bf16 in 4 VALU instructions, pre-packed.
static __device__ inline bf16x8 cvt8(f32x4 lo, f32x4 hi) {
    int i0, i1, i2, i3;
    asm("v_cvt_pk_bf16_f32 %0, %1, %2" : "=v"(i0) : "v"(lo[0]), "v"(lo[1]));
    asm("v_cvt_pk_bf16_f32 %0, %1, %2" : "=v"(i1) : "v"(lo[2]), "v"(lo[3]));
    asm("v_cvt_pk_bf16_f32 %0, %1, %2" : "=v"(i2) : "v"(hi[0]), "v"(hi[1]));
    asm("v_cvt_pk_bf16_f32 %0, %1, %2" : "=v"(i3) : "v"(hi[2]), "v"(hi[3]));
    i32x4 w = {i0, i1, i2, i3};
    return __builtin_bit_cast(bf16x8, w);
}

// R6 epilogue (measured-best): bias+silu+dot(W2), 16-lane allreduce,
// uni-molecule fast path, run atomics from l15==0 lanes.
static __device__ __forceinline__ void epilogue_store(
    const f32x4* acc, const float* bb, const float* w2v, float b2v,
    int tile, int mv, int lane, int l15, int g, int n_atoms,
    float* __restrict__ out)
{
    float p[4];
    #pragma unroll
    for (int j = 0; j < 4; ++j) {
        float s = 0.f;
        #pragma unroll
        for (int nt = 0; nt < 4; ++nt) {
            float z = acc[nt][j] + bb[nt];
            float e = __expf(-z);
            float h = z * __builtin_amdgcn_rcpf(1.f + e);  // ~1ulp, fine at tol
            s += h * w2v[nt];
        }
        p[j] = s;
    }

    const int  first = __shfl(mv, 0);
    const bool full  = (tile * 16 + 16) <= n_atoms;
    const bool uni   = full && (__all(mv == first) != 0);

    if (uni) {
        float s = p[0] + p[1] + p[2] + p[3];
        #pragma unroll
        for (int m = 1; m < 64; m <<= 1)
            s += __shfl_xor(s, m, 64);
        if (lane == 0)
            atomicAdd(&out[first], s + 16.0f * b2v);
    } else {
        int ia[4];
        #pragma unroll
        for (int j = 0; j < 4; ++j)
            ia[j] = __shfl(mv, g * 4 + j);
        #pragma unroll
        for (int m = 1; m < 16; m <<= 1) {
            #pragma unroll
            for (int j = 0; j < 4; ++j)
                p[j] += __shfl_xor(p[j], m, 64);
        }
        if (l15 == 0) {
            #pragma unroll
            for (int j = 0; j < 4; ++j) {
                int atom = tile * 16 + g * 4 + j;
                if (atom < n_atoms)
                    atomicAdd(&out[ia[j]], p[j] + b2v);
            }
        }
    }
}

__global__ __launch_bounds__(TPB, 2)   // 2-deep pipeline: ~200 VGPR, 2 waves/SIMD
void atomwise_mfma_kernel(const float* __restrict__ x,
                          const float* __restrict__ W1,
                          const float* __restrict__ b1,
                          const float* __restrict__ W2,
                          const float* __restrict__ b2,
                          const int*   __restrict__ idx_m,
                          float*       __restrict__ out,
                          int n_atoms)
{
    __shared__ short w1t[N_HID][N_IN + LDS_PAD];   // W1^T in bf16

    const int tid = threadIdx.x;

    // ---- one-time: stage W1^T (bf16) into LDS. W1 is [128][64] row-major ----
    for (int e = tid; e < N_IN * N_HID; e += TPB) {
        int k = e >> 6;     // 0..127
        int n = e & 63;     // 0..63
        w1t[n][k] = f2bf(W1[e]);
    }
    __syncthreads();

    const int lane = tid & 63;
    const int wv   = tid >> 6;
    const int l15  = lane & 15;
    const int g    = lane >> 4;     // 0..3 (k-group; also selects atoms g*4..g*4+3)

    // ---- hoist full B operand into registers, K-slot bijection pi(kt,g,e) =
    //      (2kt+(e>>2))*16 + g*4 + (e&3)  (matches A-side contiguous-64B loads) ----
    bf16x8 bfrag[4][4];             // [kt][nt]
    #pragma unroll
    for (int kt = 0; kt < 4; ++kt)
        #pragma unroll
        for (int nt = 0; nt < 4; ++nt) {
            const short* rp = &w1t[nt * 16 + l15][kt * 32 + g * 4];
            s16x4 q0 = *reinterpret_cast<const s16x4*>(rp);
            s16x4 q1 = *reinterpret_cast<const s16x4*>(rp + 16);
            bf16x8 b;
            b[0] = q0[0]; b[1] = q0[1]; b[2] = q0[2]; b[3] = q0[3];
            b[4] = q1[0]; b[5] = q1[1]; b[6] = q1[2]; b[7] = q1[3];
            bfrag[kt][nt] = b;
        }

    // per-lane channel constants: channel = nt*16 + l15
    float bb[4], w2v[4];
    #pragma unroll
    for (int nt = 0; nt < 4; ++nt) {
        bb[nt]  = b1[nt * 16 + l15];
        w2v[nt] = W2[nt * 16 + l15];
    }
    const float b2v = b2[0];

    const int n_tiles = (n_atoms + 15) >> 4;
    const int step    = gridDim.x * WAVES_PER_BLOCK;

    int tA = blockIdx.x * WAVES_PER_BLOCK + wv;
    if (tA >= n_tiles) return;
    int  tB   = tA + step;
    bool hasB = tB < n_tiles;

#define LOADX(BUF, MVDST, TT) do {                                        \
        int row_  = (TT) * 16 + l15;                                      \
        int rowc_ = row_ < n_atoms ? row_ : (n_atoms - 1);                \
        const float* xp_ = x + (size_t)rowc_ * N_IN + g * 4;              \
        _Pragma("unroll")                                                 \
        for (int j_ = 0; j_ < 8; ++j_)                                    \
            BUF[j_] = *reinterpret_cast<const f32x4*>(xp_ + j_ * 16);     \
        MVDST = idx_m[rowc_];                                             \
    } while (0)

    // ---- prologue: fill both pipeline slots ----
    f32x4 xfA[8], xfB[8];
    int mvA = 0, mvB = 0;
    LOADX(xfA, mvA, tA);
    if (hasB) LOADX(xfB, mvB, tB);

    int  tA2 = 0, tB2 = 0, nmvA = 0, nmvB = 0;
    bool hA2 = false, hB2 = false;

    while (true) {
        // ============ stage A: tile tA (loads issued 2 stages ago) ============
        {
            bf16x8 a[4];
            #pragma unroll
            for (int kt = 0; kt < 4; ++kt)
                a[kt] = cvt8(xfA[2 * kt], xfA[2 * kt + 1]);

            tA2 = tA + 2 * step;
            hA2 = tA2 < n_tiles;
            if (hA2) LOADX(xfA, nmvA, tA2);     // re-arm slot A immediately

            f32x4 acc[4] = {};
            #pragma unroll
            for (int kt = 0; kt < 4; ++kt)
                #pragma unroll
                for (int nt = 0; nt < 4; ++nt)
                    acc[nt] = __builtin_amdgcn_mfma_f32_16x16x32_bf16(
                                  a[kt], bfrag[kt][nt], acc[nt], 0, 0, 0);

            epilogue_store(acc, bb, w2v, b2v, tA, mvA, lane, l15, g, n_atoms, out);
        }
        if (!hasB) break;

        // ============ stage B: tile tB ============
        {
            bf16x8 a[4];
            #pragma unroll
            for (int kt = 0; kt < 4; ++kt)
                a[kt] = cvt8(xfB[2 * kt], xfB[2 * kt + 1]);

            tB2 = tB + 2 * step;
            hB2 = tB2 < n_tiles;
            if (hB2) LOADX(xfB, nmvB, tB2);     // re-arm slot B

            f32x4 acc[4] = {};
            #pragma unroll
            for (int kt = 0; kt < 4; ++kt)
                #pragma unroll
                for (int nt = 0; nt < 4; ++nt)
                    acc[nt] = __builtin_amdgcn_mfma_f32_16x16x32_bf16(
                                  a[kt], bfrag[kt][nt], acc[nt], 0, 0, 0);

            epilogue_store(acc, bb, w2v, b2v, tB, mvB, lane, l15, g, n_atoms, out);
        }
        if (!hA2) break;

        tA = tA2; mvA = nmvA;
        if (hB2) { tB = tB2; mvB = nmvB; }
        hasB = hB2;
    }
#undef LOADX
}

extern "C" void kernel_launch(void* const* d_in, const int* in_sizes, int n_in,
                              void* d_out, int out_size, void* d_ws, size_t ws_size,
                              hipStream_t stream) {
    const float* x   = (const float*)d_in[0];
    const float* W1  = (const float*)d_in[1];
    const float* b1  = (const float*)d_in[2];
    const float* W2  = (const float*)d_in[3];
    const float* b2  = (const float*)d_in[4];
    const int*   idx = (const int*)d_in[5];
    // d_in[6] = num_segments (scalar) — equals out_size

    const int n_atoms = in_sizes[0] / N_IN;
    float* out = (float*)d_out;

    hipMemsetAsync(d_out, 0, (size_t)out_size * sizeof(float), stream);

    const int blocks = 2048;
    atomwise_mfma_kernel<<<blocks, TPB, 0, stream>>>(
        x, W1, b1, W2, b2, idx, out, n_atoms);
}